// Round 3
// baseline (314.382 us; speedup 1.0000x reference)
//
#include <hip/hip_runtime.h>
#include <hip/hip_bf16.h>

// Problem constants (match reference setup_inputs)
constexpr int B       = 64;
constexpr int S       = 4096;
constexpr int D       = 128;
constexpr int NC      = 64;    // N_CELLS
constexpr int DTH     = 63;    // d_theta = NC - 1
constexpr int NSTEPS  = 50;
constexpr int SPLIT   = 16;    // S-chunks per batch
constexpr int SC      = S / SPLIT;  // 256 rows per chunk

// Workspace layout (bytes):
//   [0,     256)   : int   ctr[B]        -- zeroed by memset node each call
//   [1024,  33792) : float ab[B*128]     -- cell coefficients
//   [36864, 561152): float part[B*SPLIT*D]
constexpr size_t WS_AB_OFF   = 1024;
constexpr size_t WS_PART_OFF = 36864;
constexpr size_t WS_NEEDED   = WS_PART_OFF + (size_t)B * SPLIT * D * sizeof(float);

// ---------------------------------------------------------------------------
// Single fused kernel: per-chunk column reduce -> (last block per batch)
// fold+theta+A -> per-batch spin -> 50-step Euler integration.
// 1024 blocks x 256 threads: 4 blocks/CU vs capacity 8 -> all co-resident,
// so the per-batch spin cannot deadlock.
// ---------------------------------------------------------------------------
__global__ __launch_bounds__(256) void cpab_fused(const float* __restrict__ in,
                                                  const float* __restrict__ W,
                                                  const float* __restrict__ bloc,
                                                  const float* __restrict__ basis,
                                                  float* __restrict__ out,
                                                  int*   __restrict__ ctr,
                                                  float* __restrict__ ab,
                                                  float* __restrict__ part) {
    const int blk   = blockIdx.x;          // 0 .. B*SPLIT-1
    const int b     = blk >> 4;            // / SPLIT
    const int chunk = blk & 15;            // % SPLIT
    const int t     = threadIdx.x;         // 0..255
    const int d4    = t & 31;              // which float4 of the 32 per row
    const int srow  = t >> 5;              // 0..7

    // ---- Phase 1: column partial sums over this chunk's SC rows -----------
    const float4* base = reinterpret_cast<const float4*>(
        in + (size_t)b * S * D + (size_t)chunk * SC * D);

    float4 acc = make_float4(0.f, 0.f, 0.f, 0.f);
    for (int s = srow; s < SC; s += 8) {
        float4 v = base[s * 32 + d4];
        acc.x += v.x; acc.y += v.y; acc.z += v.z; acc.w += v.w;
    }

    __shared__ float4 sm[256];
    sm[t] = acc;
    __syncthreads();

    if (t < 32) {
        float4 a = sm[t];
        #pragma unroll
        for (int r = 1; r < 8; ++r) {
            float4 v = sm[r * 32 + t];
            a.x += v.x; a.y += v.y; a.z += v.z; a.w += v.w;
        }
        reinterpret_cast<float4*>(part + (size_t)(b * SPLIT + chunk) * D)[d4] = a;
    }
    __syncthreads();             // all partial stores issued (vmcnt drained)
    __threadfence();             // publish partials device-wide (L2 writeback)

    __shared__ int s_last;
    if (t == 0) {
        int old = atomicAdd(&ctr[b], 1);
        s_last = (old == SPLIT - 1);
    }
    __syncthreads();

    // ---- Phase 2 (one block per batch): fold -> theta -> A ----------------
    if (s_last) {
        __threadfence();         // acquire: invalidate caches before reading part
        __shared__ float s_mean[D];
        __shared__ float s_theta[64];

        if (t < D) {
            float tot = 0.f;
            #pragma unroll
            for (int c = 0; c < SPLIT; ++c)
                tot += __hip_atomic_load(part + (size_t)(b * SPLIT + c) * D + t,
                                         __ATOMIC_RELAXED, __HIP_MEMORY_SCOPE_AGENT);
            s_mean[t] = tot * (1.0f / (float)S);
        }
        __syncthreads();

        if (t < DTH) {
            float th = bloc[t];
            for (int d = 0; d < D; ++d)
                th += s_mean[d] * W[d * DTH + t];
            s_theta[t] = th;
        }
        __syncthreads();

        if (t < 128) {
            float a = 0.f;
            for (int j = 0; j < DTH; ++j)
                a += s_theta[j] * basis[t * DTH + j];
            ab[b * 128 + t] = a;
        }
        __syncthreads();         // ab stores drained
        __threadfence();         // publish ab
        if (t == 0) atomicAdd(&ctr[b], 1);   // ctr[b] = SPLIT+1 -> "ab ready"
    }

    // ---- Phase 3: wait for this batch's A, then integrate -----------------
    if (t == 0) {
        while (__hip_atomic_load(&ctr[b], __ATOMIC_ACQUIRE,
                                 __HIP_MEMORY_SCOPE_AGENT) <= SPLIT) {
            __builtin_amdgcn_s_sleep(2);
        }
    }
    __syncthreads();
    __threadfence();             // acquire for ab

    __shared__ float s_ab[128];
    if (t < 128)
        s_ab[t] = __hip_atomic_load(ab + b * 128 + t,
                                    __ATOMIC_RELAXED, __HIP_MEMORY_SCOPE_AGENT);
    __syncthreads();

    const int s = chunk * 256 + t;
    float x = (float)s * (1.0f / (float)(S - 1));
    const float dt = 1.0f / (float)NSTEPS;

    #pragma unroll
    for (int it = 0; it < NSTEPS; ++it) {
        int c = (int)(x * (float)NC);          // trunc toward zero == astype(int32)
        c = c < 0 ? 0 : (c > NC - 1 ? NC - 1 : c);
        float a  = s_ab[2 * c];
        float bb = s_ab[2 * c + 1];
        x = x + (a * x + bb) * dt;
    }

    out[(size_t)b * S + s] = x;
}

// ---------------------------------------------------------------------------
// Fallback 3-kernel path (proven in R1) if ws_size is too small.
// ---------------------------------------------------------------------------
__global__ __launch_bounds__(256) void cpab_reduce(const float* __restrict__ in,
                                                   float* __restrict__ part) {
    const int blk   = blockIdx.x;
    const int b     = blk / SPLIT;
    const int chunk = blk % SPLIT;
    const int t     = threadIdx.x;
    const int d4    = t & 31;
    const int srow  = t >> 5;

    const float4* base = reinterpret_cast<const float4*>(
        in + (size_t)b * S * D + (size_t)chunk * SC * D);

    float4 acc = make_float4(0.f, 0.f, 0.f, 0.f);
    for (int s = srow; s < SC; s += 8) {
        float4 v = base[s * 32 + d4];
        acc.x += v.x; acc.y += v.y; acc.z += v.z; acc.w += v.w;
    }

    __shared__ float4 sm[256];
    sm[t] = acc;
    __syncthreads();

    if (t < 32) {
        float4 a = sm[t];
        #pragma unroll
        for (int r = 1; r < 8; ++r) {
            float4 v = sm[r * 32 + t];
            a.x += v.x; a.y += v.y; a.z += v.z; a.w += v.w;
        }
        reinterpret_cast<float4*>(part + (size_t)(b * SPLIT + chunk) * D)[d4] = a;
    }
}

__global__ __launch_bounds__(128) void cpab_theta(const float* __restrict__ part,
                                                  const float* __restrict__ W,
                                                  const float* __restrict__ bloc,
                                                  const float* __restrict__ basis,
                                                  float* __restrict__ Aout) {
    const int b = blockIdx.x;
    const int t = threadIdx.x;

    __shared__ float s_mean[D];
    __shared__ float s_theta[DTH];

    float tot = 0.f;
    #pragma unroll
    for (int c = 0; c < SPLIT; ++c)
        tot += part[(size_t)(b * SPLIT + c) * D + t];
    s_mean[t] = tot * (1.0f / (float)S);
    __syncthreads();

    if (t < DTH) {
        float th = bloc[t];
        for (int d = 0; d < D; ++d)
            th += s_mean[d] * W[d * DTH + t];
        s_theta[t] = th;
    }
    __syncthreads();

    float acc = 0.f;
    for (int j = 0; j < DTH; ++j)
        acc += s_theta[j] * basis[t * DTH + j];
    Aout[b * 128 + t] = acc;
}

__global__ __launch_bounds__(256) void cpab_warp(const float* __restrict__ Aab,
                                                 float* __restrict__ out) {
    const int blk   = blockIdx.x;
    const int b     = blk >> 4;
    const int chunk = blk & 15;
    const int t     = threadIdx.x;

    __shared__ float ab[128];
    if (t < 128) ab[t] = Aab[b * 128 + t];
    __syncthreads();

    const int s = chunk * 256 + t;
    float x = (float)s * (1.0f / (float)(S - 1));
    const float dt = 1.0f / (float)NSTEPS;

    #pragma unroll
    for (int it = 0; it < NSTEPS; ++it) {
        int c = (int)(x * (float)NC);
        c = c < 0 ? 0 : (c > NC - 1 ? NC - 1 : c);
        float a  = ab[2 * c];
        float bb = ab[2 * c + 1];
        x = x + (a * x + bb) * dt;
    }

    out[(size_t)b * S + s] = x;
}

extern "C" void kernel_launch(void* const* d_in, const int* in_sizes, int n_in,
                              void* d_out, int out_size, void* d_ws, size_t ws_size,
                              hipStream_t stream) {
    const float* in_seq = (const float*)d_in[0];  // (B, S, D)
    const float* W_loc  = (const float*)d_in[1];  // (D, DTH)
    const float* b_loc  = (const float*)d_in[2];  // (DTH,)
    const float* basis  = (const float*)d_in[3];  // (2*NC, DTH)
    float*       out    = (float*)d_out;          // (B, S)

    if (ws_size >= WS_NEEDED) {
        char* ws   = (char*)d_ws;
        int*  ctr  = (int*)ws;
        float* ab  = (float*)(ws + WS_AB_OFF);
        float* part = (float*)(ws + WS_PART_OFF);

        hipMemsetAsync(ctr, 0, B * sizeof(int), stream);
        cpab_fused<<<B * SPLIT, 256, 0, stream>>>(in_seq, W_loc, b_loc, basis,
                                                  out, ctr, ab, part);
    } else {
        // 3-kernel fallback: partials in d_out (consumed before overwrite).
        float* part = out;
        float* Aab  = (float*)d_ws;
        cpab_reduce<<<B * SPLIT, 256, 0, stream>>>(in_seq, part);
        cpab_theta<<<B, 128, 0, stream>>>(part, W_loc, b_loc, basis, Aab);
        cpab_warp<<<B * (S / 256), 256, 0, stream>>>(Aab, out);
    }
}

// Round 4
// 36.154 us; speedup vs baseline: 8.6955x; 8.6955x over previous
//
#include <hip/hip_runtime.h>
#include <hip/hip_bf16.h>

// Problem constants (match reference setup_inputs)
constexpr int B       = 64;
constexpr int S       = 4096;
constexpr int D       = 128;
constexpr int NC      = 64;    // N_CELLS
constexpr int DTH     = 63;    // d_theta = NC - 1
constexpr int NSTEPS  = 50;

constexpr int SPLIT   = 32;          // S-chunks per batch for the reduction
constexpr int SC      = S / SPLIT;   // 128 rows per chunk

// ---------------------------------------------------------------------------
// Stage 1: partial column sums of input_seq over S.
//   in   : (B, S, D) f32
//   part : (B*SPLIT, D) f32
// 2048 blocks x 256 threads = 8 blocks/CU (forced via launch_bounds) ->
// 32 waves/CU. Each thread: 16 float4 loads, unrolled with 4 independent
// accumulators for deep MLP (input is L3-resident during timed replays,
// so the limit is outstanding-request count, not HBM).
// ---------------------------------------------------------------------------
__global__ __launch_bounds__(256, 8) void cpab_reduce(const float* __restrict__ in,
                                                      float* __restrict__ part) {
    const int blk   = blockIdx.x;          // 0 .. B*SPLIT-1
    const int b     = blk >> 5;            // / SPLIT
    const int chunk = blk & (SPLIT - 1);   // % SPLIT
    const int t     = threadIdx.x;         // 0..255
    const int d4    = t & 31;              // which float4 of the 32 per row
    const int srow  = t >> 5;              // 0..7

    const float4* base = reinterpret_cast<const float4*>(
        in + (size_t)b * S * D + (size_t)chunk * SC * D);

    // rows handled by this thread: srow + 8*i, i = 0..15
    float4 a0 = make_float4(0.f, 0.f, 0.f, 0.f);
    float4 a1 = a0, a2 = a0, a3 = a0;
    #pragma unroll
    for (int i = 0; i < 16; i += 4) {
        float4 v0 = base[(srow + (i + 0) * 8) * 32 + d4];
        float4 v1 = base[(srow + (i + 1) * 8) * 32 + d4];
        float4 v2 = base[(srow + (i + 2) * 8) * 32 + d4];
        float4 v3 = base[(srow + (i + 3) * 8) * 32 + d4];
        a0.x += v0.x; a0.y += v0.y; a0.z += v0.z; a0.w += v0.w;
        a1.x += v1.x; a1.y += v1.y; a1.z += v1.z; a1.w += v1.w;
        a2.x += v2.x; a2.y += v2.y; a2.z += v2.z; a2.w += v2.w;
        a3.x += v3.x; a3.y += v3.y; a3.z += v3.z; a3.w += v3.w;
    }
    a0.x += a1.x; a0.y += a1.y; a0.z += a1.z; a0.w += a1.w;
    a2.x += a3.x; a2.y += a3.y; a2.z += a3.z; a2.w += a3.w;
    a0.x += a2.x; a0.y += a2.y; a0.z += a2.z; a0.w += a2.w;

    __shared__ float4 sm[256];
    sm[t] = a0;
    __syncthreads();

    if (t < 32) {
        float4 a = sm[t];
        #pragma unroll
        for (int r = 1; r < 8; ++r) {
            float4 v = sm[r * 32 + t];
            a.x += v.x; a.y += v.y; a.z += v.z; a.w += v.w;
        }
        reinterpret_cast<float4*>(part + (size_t)(b * SPLIT + chunk) * D)[d4] = a;
    }
}

// ---------------------------------------------------------------------------
// Stage 2: fold partials -> mean -> theta -> A = theta @ basis^T
// One block per batch, 128 threads. (B, 128) result in d_ws.
// ---------------------------------------------------------------------------
__global__ __launch_bounds__(128) void cpab_theta(const float* __restrict__ part,
                                                  const float* __restrict__ W,
                                                  const float* __restrict__ bloc,
                                                  const float* __restrict__ basis,
                                                  float* __restrict__ Aout) {
    const int b = blockIdx.x;   // 0..B-1
    const int t = threadIdx.x;  // 0..127

    __shared__ float s_mean[D];
    __shared__ float s_theta[DTH];

    float tot = 0.f;
    #pragma unroll
    for (int c = 0; c < SPLIT; ++c)
        tot += part[(size_t)(b * SPLIT + c) * D + t];
    s_mean[t] = tot * (1.0f / (float)S);
    __syncthreads();

    if (t < DTH) {
        float th = bloc[t];
        #pragma unroll 8
        for (int d = 0; d < D; ++d)
            th += s_mean[d] * W[d * DTH + t];
        s_theta[t] = th;
    }
    __syncthreads();

    float acc = 0.f;
    for (int j = 0; j < DTH; ++j)
        acc += s_theta[j] * basis[t * DTH + j];
    Aout[b * 128 + t] = acc;
}

// ---------------------------------------------------------------------------
// Stage 3: CPAB warp — 50 Euler steps per grid point.
// One block per 256 consecutive grid points of one batch (1024 blocks).
// ---------------------------------------------------------------------------
__global__ __launch_bounds__(256) void cpab_warp(const float* __restrict__ Aab,
                                                 float* __restrict__ out) {
    const int blk   = blockIdx.x;          // B * (S/256)
    const int b     = blk >> 4;
    const int chunk = blk & 15;
    const int t     = threadIdx.x;

    __shared__ float ab[128];
    if (t < 128) ab[t] = Aab[b * 128 + t];
    __syncthreads();

    const int s = chunk * 256 + t;
    float x = (float)s * (1.0f / (float)(S - 1));
    const float dt = 1.0f / (float)NSTEPS;

    #pragma unroll
    for (int it = 0; it < NSTEPS; ++it) {
        int c = (int)(x * (float)NC);          // trunc toward zero == astype(int32)
        c = c < 0 ? 0 : (c > NC - 1 ? NC - 1 : c);
        float a  = ab[2 * c];
        float bb = ab[2 * c + 1];
        x = x + (a * x + bb) * dt;
    }

    out[(size_t)b * S + s] = x;
}

extern "C" void kernel_launch(void* const* d_in, const int* in_sizes, int n_in,
                              void* d_out, int out_size, void* d_ws, size_t ws_size,
                              hipStream_t stream) {
    const float* in_seq = (const float*)d_in[0];  // (B, S, D)
    const float* W_loc  = (const float*)d_in[1];  // (D, DTH)
    const float* b_loc  = (const float*)d_in[2];  // (DTH,)
    const float* basis  = (const float*)d_in[3];  // (2*NC, DTH)
    float*       out    = (float*)d_out;          // (B, S)

    // Workspace: partials (B*SPLIT*D = 1 MiB) + A coeffs (B*128 = 32 KiB).
    const size_t part_bytes = (size_t)B * SPLIT * D * sizeof(float);
    float* part = (float*)d_ws;
    float* Aab  = (float*)((char*)d_ws + part_bytes);

    cpab_reduce<<<B * SPLIT, 256, 0, stream>>>(in_seq, part);
    cpab_theta<<<B, 128, 0, stream>>>(part, W_loc, b_loc, basis, Aab);
    cpab_warp<<<B * (S / 256), 256, 0, stream>>>(Aab, out);
}